// Round 4
// baseline (241.386 us; speedup 1.0000x reference)
//
#include <hip/hip_runtime.h>

typedef __attribute__((ext_vector_type(8))) short short8;
typedef __attribute__((ext_vector_type(4))) float f32x4;
typedef __attribute__((ext_vector_type(4))) unsigned uint4v;

#define NWAVES 2
#define BLOCK (64 * NWAVES)
#define TB 8192                       // T buffer: 64 rows x 128 B bf16
#define WBYTES (TB + 6 * 64 * 4)      // + mask area mkT[6][64] u32 = 9728 B/wave

__device__ __forceinline__ unsigned short f2bf(float f) {
    unsigned u = __builtin_bit_cast(unsigned, f);
    u += 0x7FFFu + ((u >> 16) & 1u);          // round-to-nearest-even
    return (unsigned short)(u >> 16);
}

// swizzled T-buffer byte address: row in [0,64), slot = 16B unit of 8 bf16
__device__ __forceinline__ int taddr(int row, int slot) {
    return row * 128 + (((slot ^ (row & 7)) << 4));
}

// bf16 B-fragment for mfma_f32_16x16x32_bf16: B[k][n], lane gives (col, kbase).
__device__ __forceinline__ short8 loadB(const float* __restrict__ W, int Nout, int Kin,
                                        int kbase, int col) {
    short8 r;
#pragma unroll
    for (int i = 0; i < 8; ++i) {
        int k = kbase + i;
        float v = (k < Kin && col < Nout) ? W[k * Nout + col] : 0.0f;
        r[i] = (short)f2bf(v);
    }
    return r;
}

// ---------- forward layer in registers (exact fp32, blocked 16-wide) --------
template<int K, int N>
__device__ __forceinline__ void fwd_layer_reg(const float* __restrict__ W,
                                              const float* __restrict__ b,
                                              const float (&in)[K], float (&out)[N],
                                              unsigned long long& mask)
{
    mask = 0ULL;
#pragma unroll
    for (int jb = 0; jb < N; jb += 16) {
        float acc[16];
#pragma unroll
        for (int j = 0; j < 16; ++j) acc[j] = b[jb + j];
#pragma unroll 8
        for (int k = 0; k < K; ++k) {
            const float cv = in[k];
#pragma unroll
            for (int j = 0; j < 16; ++j) acc[j] = fmaf(cv, W[k * N + jb + j], acc[j]);
        }
#pragma unroll
        for (int j = 0; j < 16; ++j) {
            const bool p = acc[j] > 0.0f;
            mask |= ((unsigned long long)(p ? 1 : 0)) << (jb + j);
            out[jb + j] = p ? acc[j] : 0.0f;
        }
    }
}

// ---------- tangent epilogue: mask (one b128 read), cvt bf16, swizzled write -
// C/D layout (verified): col = lane&15, row = (lane>>4)*4 + reg.  Rows = samples.
template<int WORD0, int WSHIFT>
__device__ __forceinline__ void epi_store(unsigned char* wb, const unsigned* mkT,
                                          f32x4 c, int mt, int nt, int lane)
{
    const int col = lane & 15, G = lane >> 4;
    const int unit = nt * 16 + col;
    const int word = WORD0 + (WSHIFT ? (unit >> 5) : 0);
    const int bit  = unit & 31;
    const int R0 = mt * 16 + G * 4;
    const uint4v mw = *(const uint4v*)(mkT + word * 64 + R0);
    const int slot = unit >> 3;
    const int off = (unit & 7) * 2;
#pragma unroll
    for (int i = 0; i < 4; ++i) {
        const int R = R0 + i;
        const float v = ((mw[i] >> bit) & 1u) ? c[i] : 0.0f;
        *(unsigned short*)(wb + R * 128 + (((slot ^ (R & 7)) << 4) | off)) = f2bf(v);
    }
}

// ---------- one tangent GEMM layer, in-place in the 64-row T buffer ---------
template<int KT, int NT, int WORD0, int WSHIFT>
__device__ __forceinline__ void tan_layer_mfma(unsigned char* wb, const unsigned* mkT,
                                               const short8* Bf, int lane)
{
    const int G = lane >> 4;
    const int r15 = lane & 15;
#pragma unroll
    for (int mt = 0; mt < 4; ++mt) {
        const int R = mt * 16 + r15;
        short8 a[KT];
#pragma unroll
        for (int kt = 0; kt < KT; ++kt)
            a[kt] = *(const short8*)(wb + taddr(R, 4 * kt + G));
#pragma unroll
        for (int nt = 0; nt < NT; ++nt) {
            f32x4 c = {0.f, 0.f, 0.f, 0.f};
#pragma unroll
            for (int kt = 0; kt < KT; ++kt)
                c = __builtin_amdgcn_mfma_f32_16x16x32_bf16(a[kt], Bf[kt * NT + nt], c, 0, 0, 0);
            epi_store<WORD0, WSHIFT>(wb, mkT, c, mt, nt, lane);
        }
    }
}

// ---------- final layer: T4 @ W5 -> F column r (adds identity) --------------
__device__ __forceinline__ void tan_final(unsigned char* wb, const short8* B5,
                                          int lane, int r,
                                          float* __restrict__ out_F, int sbase)
{
    const int G = lane >> 4, col = lane & 15;
    const int r15 = lane & 15;
#pragma unroll
    for (int mt = 0; mt < 4; ++mt) {
        const int R = mt * 16 + r15;
        short8 a0 = *(const short8*)(wb + taddr(R, G));
        short8 a1 = *(const short8*)(wb + taddr(R, 4 + G));
        f32x4 c = {0.f, 0.f, 0.f, 0.f};
        c = __builtin_amdgcn_mfma_f32_16x16x32_bf16(a0, B5[0], c, 0, 0, 0);
        c = __builtin_amdgcn_mfma_f32_16x16x32_bf16(a1, B5[1], c, 0, 0, 0);
        if (col < 4) {
            const int R0 = mt * 16 + G * 4;
#pragma unroll
            for (int i = 0; i < 4; ++i) {
                const float v = c[i] + ((col == r) ? 1.0f : 0.0f);
                out_F[(size_t)(sbase + R0 + i) * 16 + col * 4 + r] = v;
            }
        }
    }
}

__global__ __launch_bounds__(BLOCK, 3)
void mlp_jac_kernel(
    const float* __restrict__ W1, const float* __restrict__ b1,
    const float* __restrict__ W2, const float* __restrict__ b2,
    const float* __restrict__ W3, const float* __restrict__ b3,
    const float* __restrict__ W4, const float* __restrict__ b4,
    const float* __restrict__ W5, const float* __restrict__ b5,
    const float* __restrict__ xin,
    float* __restrict__ out_state, float* __restrict__ out_F, int Btot)
{
    __shared__ __align__(16) unsigned char smem[NWAVES][WBYTES];
    const int tid = threadIdx.x;
    const int wid = tid >> 6;
    const int lane = tid & 63;
    const int sbase = blockIdx.x * BLOCK + wid * 64;   // wave's first sample
    if (sbase >= Btot) return;

    unsigned char* wb = smem[wid];
    unsigned* mkT = (unsigned*)(wb + TB);              // mkT[word][sample]

    const int s_my = sbase + lane;
    const float4 xv = *reinterpret_cast<const float4*>(xin + 4 * s_my);
    float xa[4] = {xv.x, xv.y, xv.z, xv.w};

    // ============ phase 1: fp32 forward entirely in registers ==============
    unsigned long long m1w, m2w, m3, m4;
    float h1[32], h2[32], h3[64];
    fwd_layer_reg<4, 32>(W1, b1, xa, h1, m1w);
    fwd_layer_reg<32, 32>(W2, b2, h1, h2, m2w);
    fwd_layer_reg<32, 64>(W3, b3, h2, h3, m3);
    const unsigned m1 = (unsigned)m1w, m2 = (unsigned)m2w;

    // layer4 + layer5 fused: h4 never materialized
    m4 = 0ULL;
    float y[4] = {b5[0], b5[1], b5[2], b5[3]};
#pragma unroll
    for (int jb = 0; jb < 64; jb += 16) {
        float acc[16];
#pragma unroll
        for (int j = 0; j < 16; ++j) acc[j] = b4[jb + j];
#pragma unroll 8
        for (int k = 0; k < 64; ++k) {
            const float cv = h3[k];
#pragma unroll
            for (int j = 0; j < 16; ++j) acc[j] = fmaf(cv, W4[k * 64 + jb + j], acc[j]);
        }
#pragma unroll
        for (int j = 0; j < 16; ++j) {
            const bool p = acc[j] > 0.0f;
            m4 |= ((unsigned long long)(p ? 1 : 0)) << (jb + j);
            const float hv = p ? acc[j] : 0.0f;
#pragma unroll
            for (int i = 0; i < 4; ++i) y[i] = fmaf(hv, W5[(jb + j) * 4 + i], y[i]);
        }
    }
    {
        float4 o;
        o.x = xa[0] + y[0]; o.y = xa[1] + y[1];
        o.z = xa[2] + y[2]; o.w = xa[3] + y[3];
        *reinterpret_cast<float4*>(out_state + 4 * s_my) = o;
    }
    // masks word-major: one ds_read_b128 in the epilogue covers 4 samples
    mkT[0 * 64 + lane] = m1;
    mkT[1 * 64 + lane] = m2;
    mkT[2 * 64 + lane] = (unsigned)(m3 & 0xffffffffULL);
    mkT[3 * 64 + lane] = (unsigned)(m3 >> 32);
    mkT[4 * 64 + lane] = (unsigned)(m4 & 0xffffffffULL);
    mkT[5 * 64 + lane] = (unsigned)(m4 >> 32);

    // ============ phase 2: bf16 weight B-fragments in registers ============
    const int col = lane & 15, G = lane >> 4;
    short8 B2f[2], B3f[4], B4f[8], B5f[2];
#pragma unroll
    for (int nt = 0; nt < 2; ++nt) B2f[nt] = loadB(W2, 32, 32, 8 * G, 16 * nt + col);
#pragma unroll
    for (int nt = 0; nt < 4; ++nt) B3f[nt] = loadB(W3, 64, 32, 8 * G, 16 * nt + col);
#pragma unroll
    for (int kt = 0; kt < 2; ++kt)
#pragma unroll
        for (int nt = 0; nt < 4; ++nt)
            B4f[kt * 4 + nt] = loadB(W4, 64, 64, 32 * kt + 8 * G, 16 * nt + col);
#pragma unroll
    for (int kt = 0; kt < 2; ++kt) B5f[kt] = loadB(W5, 4, 64, 32 * kt + 8 * G, col);

    // ============ phase 3: one Jacobian column per pass ====================
    for (int r = 0; r < 4; ++r) {
        // T1[s][u] = m1[s][u] ? bf16(W1[r][u]) : 0  — identical for all rows,
        // so seed by direct masked write (each lane writes its own row).
#pragma unroll
        for (int sl = 0; sl < 4; ++sl) {
            short8 v;
#pragma unroll
            for (int e = 0; e < 8; ++e) {
                const int u = sl * 8 + e;
                v[e] = ((m1 >> u) & 1u) ? (short)f2bf(W1[r * 32 + u]) : (short)0;
            }
            *(short8*)(wb + taddr(lane, sl)) = v;
        }
        // T2 = m2 .* (T1 @ W2); T3 = m3 .* (T2 @ W3); T4 = m4 .* (T3 @ W4)
        tan_layer_mfma<1, 2, 1, 0>(wb, mkT, B2f, lane);
        tan_layer_mfma<1, 4, 2, 1>(wb, mkT, B3f, lane);
        tan_layer_mfma<2, 4, 4, 1>(wb, mkT, B4f, lane);
        // F[:, :, r] = I[:, r] + T4 @ W5
        tan_final(wb, B5f, lane, r, out_F, sbase);
    }
}

extern "C" void kernel_launch(void* const* d_in, const int* in_sizes, int n_in,
                              void* d_out, int out_size, void* d_ws, size_t ws_size,
                              hipStream_t stream)
{
    const float* W1 = (const float*)d_in[0];
    const float* b1 = (const float*)d_in[1];
    const float* W2 = (const float*)d_in[2];
    const float* b2 = (const float*)d_in[3];
    const float* W3 = (const float*)d_in[4];
    const float* b3 = (const float*)d_in[5];
    const float* W4 = (const float*)d_in[6];
    const float* b4 = (const float*)d_in[7];
    const float* W5 = (const float*)d_in[8];
    const float* b5 = (const float*)d_in[9];
    const float* xin = (const float*)d_in[10];

    const int Btot = in_sizes[10] / 4;       // last_state is (B,1,4) fp32
    float* out_state = (float*)d_out;
    float* out_F = out_state + (size_t)Btot * 4;

    const int grid = (Btot + BLOCK - 1) / BLOCK;
    mlp_jac_kernel<<<grid, BLOCK, 0, stream>>>(
        W1, b1, W2, b2, W3, b3, W4, b4, W5, b5, xin, out_state, out_F, Btot);
}